// Round 11
// baseline (1435.981 us; speedup 1.0000x reference)
//
#include <hip/hip_runtime.h>
#include <hip/hip_bf16.h>

#define Bn 32
#define Cn 256
#define Hn 48
#define Wn 48
#define HWn 2304
#define Pn 50
#define PPn 2500
#define K9 2304

typedef __attribute__((ext_vector_type(8))) short bf16x8;
typedef __attribute__((ext_vector_type(4))) float f32x4;

__device__ __forceinline__ void gload_lds16(const void* g, void* l) {
  __builtin_amdgcn_global_load_lds((const __attribute__((address_space(1))) void*)g,
                                   (__attribute__((address_space(3))) void*)l, 16, 0, 0);
}

// ---------------- zero halos of the two padded NHWC buffers ----------------
__global__ void k_zero_halo(__hip_bfloat16* p0, __hip_bfloat16* p1) {
  int hp = blockIdx.x, b = blockIdx.y, c = threadIdx.x;
  int h, w;
  if (hp < 50)       { h = 0;        w = hp; }
  else if (hp < 100) { h = 49;       w = hp - 50; }
  else if (hp < 148) { h = hp - 99;  w = 0; }
  else               { h = hp - 147; w = 49; }
  __hip_bfloat16* p = blockIdx.z == 0 ? p0 : p1;
  p[(((size_t)b * Pn + h) * Pn + w) * Cn + c] = __float2bfloat16(0.f);
}

// ---------------- weight repack: (O,C,3,3) f32 -> W2[o][t*256+ci] bf16 -----
__global__ void k_prep_w(const float* __restrict__ w, __hip_bfloat16* __restrict__ w2, int O) {
  int idx = blockIdx.x * 256 + threadIdx.x;
  if (idx >= O * K9) return;
  int o = idx / K9, k = idx - o * K9;
  int t = k >> 8, ci = k & 255;
  w2[idx] = __float2bfloat16(w[(size_t)(o * Cn + ci) * 9 + t]);
}

// ---------------- x NCHW f32 -> padded NHWC bf16 ---------------------------
__global__ void k_x_to_pad(const float* __restrict__ x, __hip_bfloat16* __restrict__ xp) {
  __shared__ float tile[64][65];
  int m0 = blockIdx.x * 64, c0 = blockIdx.y * 64, b = blockIdx.z;
  int tid = threadIdx.x;
#pragma unroll
  for (int p = 0; p < 16; ++p) {
    int cr = (tid >> 6) + p * 4;
    int mm = tid & 63;
    tile[cr][mm] = x[((size_t)(b * Cn + c0 + cr)) * HWn + m0 + mm];
  }
  __syncthreads();
#pragma unroll
  for (int p = 0; p < 16; ++p) {
    int c2 = tid & 63;
    int m2 = (tid >> 6) + p * 4;
    int mg = m0 + m2;
    int h = mg / 48, w = mg - h * 48;
    xp[(((size_t)b * Pn + h + 1) * Pn + (w + 1)) * Cn + c0 + c2] = __float2bfloat16(tile[c2][m2]);
  }
}

// ---------------- implicit conv GEMM (9-tap, NHWC padded in, bf16) ---------
// epi 0: NHWC out [b][m][O] (offsets).  epi 1: bias+relu -> padded NHWC interior.
// epi 2: bias -> NHWC [b][m][256] (a3).
__global__ __launch_bounds__(256, 2)
void k_conv_gemm(const __hip_bfloat16* __restrict__ inp, const __hip_bfloat16* __restrict__ w2,
                 const float* __restrict__ bias, __hip_bfloat16* __restrict__ out,
                 int O, int epi) {
  __shared__ __align__(16) __hip_bfloat16 As[128 * 64];
  __shared__ __align__(16) __hip_bfloat16 Bs[128 * 64];
  const int mt = blockIdx.x, nt = blockIdx.y, b = blockIdx.z;
  const int tid = threadIdx.x;
  const int wv = tid >> 6, ln = tid & 63;
  const int wr = wv >> 1, wc = wv & 1;

  const int swz = ((ln & 7) ^ (ln >> 3)) * 8;  // element offset (8 elems = 16B chunks)
  int aSp[4];
  const __hip_bfloat16* w2b[4];
#pragma unroll
  for (int i = 0; i < 4; ++i) {
    int row = wv * 32 + i * 8 + (ln >> 3);
    int gm = mt * 128 + row;
    int hh = gm / 48, ww = gm - hh * 48;
    aSp[i] = hh * Pn + ww;
    w2b[i] = w2 + (size_t)(nt * 128 + row) * K9 + swz;
  }
  const __hip_bfloat16* inb = inp + (size_t)b * (PPn * Cn) + swz;

  f32x4 acc[4][4];
  f32x4 zero = {0.f, 0.f, 0.f, 0.f};
#pragma unroll
  for (int i = 0; i < 4; ++i)
#pragma unroll
    for (int j = 0; j < 4; ++j) acc[i][j] = zero;

  const int arow0 = wr * 64 + (ln & 15);
  const int brow0 = wc * 64 + (ln & 15);
  const int kb0 = (ln >> 4) * 16;
  const int sx = (ln & 7) << 4;

#pragma unroll 1
  for (int t = 0; t < 9; ++t) {
    const int dOff = (t / 3) * Pn + (t % 3);
#pragma unroll 1
    for (int ck = 0; ck < 4; ++ck) {
#pragma unroll
      for (int i = 0; i < 4; ++i) {
        gload_lds16(inb + (size_t)(aSp[i] + dOff) * Cn + ck * 64, (void*)(As + (wv * 4 + i) * 512));
        gload_lds16(w2b[i] + t * 256 + ck * 64, (void*)(Bs + (wv * 4 + i) * 512));
      }
      __syncthreads();
#pragma unroll
      for (int kk = 0; kk < 2; ++kk) {
        const int kb = kk * 64 + kb0;
        bf16x8 af[4], bfr[4];
#pragma unroll
        for (int mi = 0; mi < 4; ++mi) {
          int r = arow0 + mi * 16;
          af[mi] = *(const bf16x8*)((const char*)As + r * 128 + (kb ^ sx));
        }
#pragma unroll
        for (int ni = 0; ni < 4; ++ni) {
          int r = brow0 + ni * 16;
          bfr[ni] = *(const bf16x8*)((const char*)Bs + r * 128 + (kb ^ sx));
        }
#pragma unroll
        for (int mi = 0; mi < 4; ++mi)
#pragma unroll
          for (int ni = 0; ni < 4; ++ni)
            acc[mi][ni] = __builtin_amdgcn_mfma_f32_16x16x32_bf16(af[mi], bfr[ni], acc[mi][ni], 0, 0, 0);
      }
      __syncthreads();
    }
  }

#pragma unroll
  for (int mi = 0; mi < 4; ++mi)
#pragma unroll
    for (int ni = 0; ni < 4; ++ni)
#pragma unroll
      for (int j = 0; j < 4; ++j) {
        int ml = wr * 64 + mi * 16 + (ln >> 4) * 4 + j;
        int ol = wc * 64 + ni * 16 + (ln & 15);
        int gm = mt * 128 + ml;
        int go = nt * 128 + ol;
        float v = acc[mi][ni][j];
        if (epi == 0) {
          out[((size_t)b * HWn + gm) * (size_t)O + go] = __float2bfloat16(v);
        } else if (epi == 1) {
          v += bias[go];
          v = v > 0.f ? v : 0.f;
          int hh = gm / 48, ww = gm - hh * 48;
          out[(((size_t)b * Pn + hh + 1) * Pn + (ww + 1)) * Cn + go] = __float2bfloat16(v);
        } else {
          v += bias[go];
          out[((size_t)b * HWn + gm) * Cn + go] = __float2bfloat16(v);
        }
      }
}

// ---------------- ConvOffset2D bilinear resample ---------------------------
__global__ void k_resample(const __hip_bfloat16* __restrict__ img,  // padded NHWC
                           const __hip_bfloat16* __restrict__ off,  // [B][2304][512]
                           __hip_bfloat16* __restrict__ outp) {     // padded NHWC
  int q = blockIdx.x, b = blockIdx.y, c = threadIdx.x;
  int dlt = (q >= 1152) ? 1 : 0;
  int pos = 2 * q - dlt * HWn;
  size_t ob = ((size_t)b * HWn + pos) * 512 + 2 * c + dlt;
  float oy = __bfloat162float(off[ob]);
  float ox = __bfloat162float(off[ob + 512]);
  int gy = q / 48, gx = q - gy * 48;
  float y = fminf(fmaxf((float)gy + oy, 0.f), 47.f);
  float x = fminf(fmaxf((float)gx + ox, 0.f), 47.f);
  float fy = floorf(y), fx = floorf(x);
  int y0 = (int)fy, x0 = (int)fx;
  int y1 = min(y0 + 1, 47), x1 = min(x0 + 1, 47);
  float wy = y - fy, wx = x - fx;
  const __hip_bfloat16* ib = img + (size_t)b * (PPn * Cn) + c;
  float v00 = __bfloat162float(ib[(size_t)((y0 + 1) * Pn + x0 + 1) * Cn]);
  float v01 = __bfloat162float(ib[(size_t)((y0 + 1) * Pn + x1 + 1) * Cn]);
  float v10 = __bfloat162float(ib[(size_t)((y1 + 1) * Pn + x0 + 1) * Cn]);
  float v11 = __bfloat162float(ib[(size_t)((y1 + 1) * Pn + x1 + 1) * Cn]);
  float r = v00 * (1 - wy) * (1 - wx) + v01 * (1 - wy) * wx + v10 * wy * (1 - wx) + v11 * wy * wx;
  outp[(((size_t)b * Pn + gy + 1) * Pn + (gx + 1)) * Cn + c] = __float2bfloat16(r);
}

// ---------------- channel sums of a3 ---------------------------------------
__global__ void k_colmeans(const __hip_bfloat16* __restrict__ a3, float* __restrict__ msum) {
  int b = blockIdx.y, m0 = blockIdx.x * 128, c = threadIdx.x;
  const __hip_bfloat16* p = a3 + ((size_t)b * HWn + m0) * Cn + c;
  float s = 0.f;
  for (int r = 0; r < 128; ++r) s += __bfloat162float(p[(size_t)r * Cn]);
  atomicAdd(&msum[b * Cn + c], s);
}

// ---------------- Gram = a3^T a3 per batch (bf16 MFMA) ---------------------
__global__ __launch_bounds__(256, 2)
void k_gram(const __hip_bfloat16* __restrict__ a3, float* __restrict__ gram) {
  __shared__ __align__(16) __hip_bfloat16 Ti[64 * 128];
  __shared__ __align__(16) __hip_bfloat16 Tj[64 * 128];
  int it = blockIdx.x, jt = blockIdx.y, b = blockIdx.z;
  int tid = threadIdx.x, wv = tid >> 6, ln = tid & 63;
  int wr = wv >> 1, wc = wv & 1;
  f32x4 acc[4][4];
  f32x4 zero = {0.f, 0.f, 0.f, 0.f};
#pragma unroll
  for (int i = 0; i < 4; ++i)
#pragma unroll
    for (int j = 0; j < 4; ++j) acc[i][j] = zero;
  const __hip_bfloat16* base = a3 + (size_t)b * HWn * Cn;
#pragma unroll 1
  for (int m0 = 0; m0 < HWn; m0 += 64) {
#pragma unroll
    for (int i = 0; i < 4; ++i) {
      int row = (wv * 4 + i) * 4 + (ln >> 4);
      int ce = (ln & 15) * 8;
      gload_lds16(base + (size_t)(m0 + row) * Cn + it * 128 + ce, (void*)(Ti + (wv * 4 + i) * 512));
      gload_lds16(base + (size_t)(m0 + row) * Cn + jt * 128 + ce, (void*)(Tj + (wv * 4 + i) * 512));
    }
    __syncthreads();
#pragma unroll
    for (int kk = 0; kk < 2; ++kk) {
      bf16x8 af[4], bfr[4];
#pragma unroll
      for (int mi = 0; mi < 4; ++mi) {
        int il = wr * 64 + mi * 16 + (ln & 15);
        bf16x8 v;
#pragma unroll
        for (int j = 0; j < 8; ++j)
          v[j] = ((const short*)Ti)[(kk * 32 + (ln >> 4) * 8 + j) * 128 + il];
        af[mi] = v;
      }
#pragma unroll
      for (int ni = 0; ni < 4; ++ni) {
        int jl = wc * 64 + ni * 16 + (ln & 15);
        bf16x8 v;
#pragma unroll
        for (int j = 0; j < 8; ++j)
          v[j] = ((const short*)Tj)[(kk * 32 + (ln >> 4) * 8 + j) * 128 + jl];
        bfr[ni] = v;
      }
#pragma unroll
      for (int mi = 0; mi < 4; ++mi)
#pragma unroll
        for (int ni = 0; ni < 4; ++ni)
          acc[mi][ni] = __builtin_amdgcn_mfma_f32_16x16x32_bf16(af[mi], bfr[ni], acc[mi][ni], 0, 0, 0);
    }
    __syncthreads();
  }
#pragma unroll
  for (int mi = 0; mi < 4; ++mi)
#pragma unroll
    for (int ni = 0; ni < 4; ++ni)
#pragma unroll
      for (int j = 0; j < 4; ++j) {
        int gi = it * 128 + wr * 64 + mi * 16 + (ln >> 4) * 4 + j;
        int gj = jt * 128 + wc * 64 + ni * 16 + (ln & 15);
        gram[((size_t)b * Cn + gi) * Cn + gj] = acc[mi][ni][j];
      }
}

// ---------------- trace of cov ---------------------------------------------
__global__ void k_trace(const float* __restrict__ gram, const float* __restrict__ msum,
                        float* __restrict__ normA) {
  __shared__ float red[256];
  int b = blockIdx.x, i = threadIdx.x;
  float g = gram[((size_t)b * Cn + i) * Cn + i];
  float mu = msum[b * Cn + i] * (1.f / 2304.f);
  red[i] = g * (1.f / 2304.f) - mu * mu;
  __syncthreads();
  for (int s = 128; s > 0; s >>= 1) {
    if (i < s) red[i] += red[i + s];
    __syncthreads();
  }
  if (i == 0) normA[b] = red[0];
}

// ---------------- Y0 = cov/normA, Z0 = I -----------------------------------
__global__ void k_initYZ(const float* __restrict__ gram, const float* __restrict__ msum,
                         const float* __restrict__ normA, float* __restrict__ Y, float* __restrict__ Z) {
  int b = blockIdx.y;
  int idx = blockIdx.x * 256 + threadIdx.x;
  int i = idx >> 8, j = idx & 255;
  float mui = msum[b * Cn + i] * (1.f / 2304.f);
  float muj = msum[b * Cn + j] * (1.f / 2304.f);
  float cov = gram[((size_t)b << 16) + idx] * (1.f / 2304.f) - mui * muj;
  Y[((size_t)b << 16) + idx] = cov / normA[b];
  Z[((size_t)b << 16) + idx] = (i == j) ? 1.f : 0.f;
}

// ---------------- batched 256x256 fp32 matmul (NS) -------------------------
// mode 0: O = 1.5I - 0.5*(A@B);  mode 1: O = A@B
__global__ __launch_bounds__(256)
void k_ns_mm(const float* __restrict__ Ag, const float* __restrict__ Bg,
             float* __restrict__ Og, int mode) {
  __shared__ float As[16][65];
  __shared__ __align__(16) float Bs[16][64];
  int ti = blockIdx.x >> 2, tj = blockIdx.x & 3;
  int b = blockIdx.y;
  const float* A = Ag + ((size_t)b << 16);
  const float* B = Bg + ((size_t)b << 16);
  int tid = threadIdx.x, tx = tid & 15, ty = tid >> 4;
  float acc[4][4] = {};
#pragma unroll 1
  for (int k0 = 0; k0 < 256; k0 += 16) {
    {
      int k = tid & 15, r0 = tid >> 4;
#pragma unroll
      for (int p = 0; p < 4; ++p) {
        int r = r0 + p * 16;
        As[k][r] = A[(size_t)(ti * 64 + r) * 256 + k0 + k];
      }
      int cc = tid & 63, kb = tid >> 6;
#pragma unroll
      for (int p = 0; p < 4; ++p) {
        int k2 = kb + p * 4;
        Bs[k2][cc] = B[(size_t)(k0 + k2) * 256 + tj * 64 + cc];
      }
    }
    __syncthreads();
#pragma unroll
    for (int kk = 0; kk < 16; ++kk) {
      float4 bv = *(const float4*)&Bs[kk][tx * 4];
      float av[4];
#pragma unroll
      for (int i2 = 0; i2 < 4; ++i2) av[i2] = As[kk][ty * 4 + i2];
#pragma unroll
      for (int i2 = 0; i2 < 4; ++i2) {
        acc[i2][0] += av[i2] * bv.x;
        acc[i2][1] += av[i2] * bv.y;
        acc[i2][2] += av[i2] * bv.z;
        acc[i2][3] += av[i2] * bv.w;
      }
    }
    __syncthreads();
  }
#pragma unroll
  for (int i2 = 0; i2 < 4; ++i2) {
    int gi = ti * 64 + ty * 4 + i2;
#pragma unroll
    for (int j = 0; j < 4; ++j) {
      int gj = tj * 64 + tx * 4 + j;
      float v = acc[i2][j];
      if (mode == 0) v = ((gi == gj) ? 1.5f : 0.f) - 0.5f * v;
      Og[((size_t)b << 16) + (size_t)gi * 256 + gj] = v;
    }
  }
}

// ---- fused NS update: z=0 computes Yn=Yc@Tt, z=1 computes Zn=Tt@Zc --------
// Same body as k_ns_mm mode 1; operand triple selected by blockIdx.z.
__global__ __launch_bounds__(256)
void k_ns_mm2(const float* __restrict__ Ycg, const float* __restrict__ Ttg,
              const float* __restrict__ Zcg, float* __restrict__ Yng,
              float* __restrict__ Zng) {
  __shared__ float As[16][65];
  __shared__ __align__(16) float Bs[16][64];
  int ti = blockIdx.x >> 2, tj = blockIdx.x & 3;
  int b = blockIdx.y;
  const float* A;
  const float* B;
  float* O;
  if (blockIdx.z == 0) { A = Ycg; B = Ttg; O = Yng; }
  else                 { A = Ttg; B = Zcg; O = Zng; }
  A += ((size_t)b << 16);
  B += ((size_t)b << 16);
  int tid = threadIdx.x, tx = tid & 15, ty = tid >> 4;
  float acc[4][4] = {};
#pragma unroll 1
  for (int k0 = 0; k0 < 256; k0 += 16) {
    {
      int k = tid & 15, r0 = tid >> 4;
#pragma unroll
      for (int p = 0; p < 4; ++p) {
        int r = r0 + p * 16;
        As[k][r] = A[(size_t)(ti * 64 + r) * 256 + k0 + k];
      }
      int cc = tid & 63, kb = tid >> 6;
#pragma unroll
      for (int p = 0; p < 4; ++p) {
        int k2 = kb + p * 4;
        Bs[k2][cc] = B[(size_t)(k0 + k2) * 256 + tj * 64 + cc];
      }
    }
    __syncthreads();
#pragma unroll
    for (int kk = 0; kk < 16; ++kk) {
      float4 bv = *(const float4*)&Bs[kk][tx * 4];
      float av[4];
#pragma unroll
      for (int i2 = 0; i2 < 4; ++i2) av[i2] = As[kk][ty * 4 + i2];
#pragma unroll
      for (int i2 = 0; i2 < 4; ++i2) {
        acc[i2][0] += av[i2] * bv.x;
        acc[i2][1] += av[i2] * bv.y;
        acc[i2][2] += av[i2] * bv.z;
        acc[i2][3] += av[i2] * bv.w;
      }
    }
    __syncthreads();
  }
#pragma unroll
  for (int i2 = 0; i2 < 4; ++i2) {
    int gi = ti * 64 + ty * 4 + i2;
#pragma unroll
    for (int j = 0; j < 4; ++j) {
      int gj = tj * 64 + tx * 4 + j;
      O[((size_t)b << 16) + (size_t)gi * 256 + gj] = acc[i2][j];
    }
  }
}

// ---------------- v = sqrt(normA)/256 * colsum(Y) --------------------------
__global__ void k_v(const float* __restrict__ Y, const float* __restrict__ normA,
                    float* __restrict__ v) {
  int b = blockIdx.x, d = threadIdx.x;
  const float* p = Y + ((size_t)b << 16) + d;
  float s = 0.f;
  for (int c = 0; c < 256; ++c) s += p[(size_t)c * 256];
  v[b * Cn + d] = s * (1.f / 256.f) * sqrtf(normA[b]);
}

// ---------------- attention MLP --------------------------------------------
__global__ void k_attn(const float* __restrict__ v, const float* __restrict__ w1,
                       const float* __restrict__ b1, const float* __restrict__ w2,
                       const float* __restrict__ b2, float* __restrict__ attn) {
  __shared__ float sv[256], sh[32];
  int b = blockIdx.x, t = threadIdx.x;
  sv[t] = v[b * Cn + t];
  __syncthreads();
  if (t < 32) {
    float s = b1[t];
    for (int c = 0; c < 256; ++c) s += sv[c] * w1[t * 256 + c];
    sh[t] = fmaxf(s, 0.f);
  }
  __syncthreads();
  float s = b2[t];
  for (int j = 0; j < 32; ++j) s += sh[j] * w2[t * 32 + j];
  attn[b * Cn + t] = 1.f / (1.f + expf(-s));
}

// ---------------- out = attn*a3 + x (NHWC->NCHW) ---------------------------
__global__ void k_final(const __hip_bfloat16* __restrict__ a3, const float* __restrict__ x,
                        const float* __restrict__ attn, float* __restrict__ out) {
  __shared__ float tile[64][65];
  int m0 = blockIdx.x * 64, c0 = blockIdx.y * 64, b = blockIdx.z;
  int tid = threadIdx.x;
#pragma unroll
  for (int p = 0; p < 16; ++p) {
    int mr = (tid >> 6) + p * 4;
    int cl = tid & 63;
    tile[mr][cl] = __bfloat162float(a3[((size_t)b * HWn + m0 + mr) * Cn + c0 + cl]);
  }
  __syncthreads();
#pragma unroll
  for (int p = 0; p < 16; ++p) {
    int m2 = tid & 63;
    int c2 = (tid >> 6) + p * 4;
    size_t gidx = ((size_t)(b * Cn + c0 + c2)) * HWn + m0 + m2;
    out[gidx] = attn[b * Cn + c0 + c2] * tile[m2][c2] + x[gidx];
  }
}

// ===========================================================================
extern "C" void kernel_launch(void* const* d_in, const int* in_sizes, int n_in,
                              void* d_out, int out_size, void* d_ws, size_t ws_size,
                              hipStream_t stream) {
  const float* x      = (const float*)d_in[0];
  const float* off_w1 = (const float*)d_in[1];
  const float* off_w2 = (const float*)d_in[2];
  const float* c1w    = (const float*)d_in[3];
  const float* c1b    = (const float*)d_in[4];
  const float* c2w    = (const float*)d_in[5];
  const float* c2b    = (const float*)d_in[6];
  const float* caw1   = (const float*)d_in[7];
  const float* cab1   = (const float*)d_in[8];
  const float* caw2   = (const float*)d_in[9];
  const float* cab2   = (const float*)d_in[10];
  float* out = (float*)d_out;

  char* ws = (char*)d_ws;
  size_t o = 0;
  auto alloc = [&](size_t n) { char* p = ws + o; o = (o + n + 255) & ~(size_t)255; return p; };

  const size_t PADB = (size_t)Bn * PPn * Cn * 2;       // 40,960,000
  __hip_bfloat16* padA = (__hip_bfloat16*)alloc(PADB); // x_pad, later a1_pad
  __hip_bfloat16* padB = (__hip_bfloat16*)alloc(PADB); // a0_pad, later a2_pad
  char* offreg = alloc((size_t)Bn * HWn * 512 * 2);    // 75.5 MB, reused by NS bufs
  __hip_bfloat16* offb = (__hip_bfloat16*)offreg;
  __hip_bfloat16* a3   = (__hip_bfloat16*)alloc((size_t)Bn * HWn * Cn * 2);
  __hip_bfloat16* w2o1 = (__hip_bfloat16*)alloc((size_t)512 * K9 * 2);
  __hip_bfloat16* w2o2 = (__hip_bfloat16*)alloc((size_t)512 * K9 * 2);
  __hip_bfloat16* w2c1 = (__hip_bfloat16*)alloc((size_t)256 * K9 * 2);
  __hip_bfloat16* w2c2 = (__hip_bfloat16*)alloc((size_t)256 * K9 * 2);
  float* msum  = (float*)alloc(Bn * Cn * 4);
  float* normA = (float*)alloc(Bn * 4);
  float* vbuf  = (float*)alloc(Bn * Cn * 4);
  float* attnb = (float*)alloc(Bn * Cn * 4);
  // NS buffers overlay the (dead-by-then) offset region
  const size_t MB = (size_t)Bn * Cn * Cn * 4; // 8,388,608
  float* gram = (float*)(offreg + 0 * MB);
  float* Ya   = (float*)(offreg + 1 * MB);
  float* Za   = (float*)(offreg + 2 * MB);
  float* Yb   = (float*)(offreg + 3 * MB);
  float* Zb   = (float*)(offreg + 4 * MB);
  float* Tt   = (float*)(offreg + 5 * MB);

  k_zero_halo<<<dim3(196, 32, 2), 256, 0, stream>>>(padA, padB);
  k_prep_w<<<dim3(4608), 256, 0, stream>>>(off_w1, w2o1, 512);
  k_prep_w<<<dim3(4608), 256, 0, stream>>>(off_w2, w2o2, 512);
  k_prep_w<<<dim3(2304), 256, 0, stream>>>(c1w, w2c1, 256);
  k_prep_w<<<dim3(2304), 256, 0, stream>>>(c2w, w2c2, 256);
  k_x_to_pad<<<dim3(36, 4, 32), 256, 0, stream>>>(x, padA);

  // off1 = conv(x); a0 = resample(x, off1)
  k_conv_gemm<<<dim3(18, 4, 32), 256, 0, stream>>>(padA, w2o1, nullptr, offb, 512, 0);
  k_resample<<<dim3(2304, 32), 256, 0, stream>>>(padA, offb, padB);
  // a1 = relu(conv1(a0))  (writes padA)
  k_conv_gemm<<<dim3(18, 2, 32), 256, 0, stream>>>(padB, w2c1, c1b, padA, 256, 1);
  // off2 = conv(a1); a2 = resample(a1, off2) (writes padB)
  k_conv_gemm<<<dim3(18, 4, 32), 256, 0, stream>>>(padA, w2o2, nullptr, offb, 512, 0);
  k_resample<<<dim3(2304, 32), 256, 0, stream>>>(padA, offb, padB);
  // a3 = conv2(a2)
  k_conv_gemm<<<dim3(18, 2, 32), 256, 0, stream>>>(padB, w2c2, c2b, a3, 256, 2);

  // SOCA
  hipMemsetAsync(msum, 0, Bn * Cn * 4, stream);
  k_colmeans<<<dim3(18, 32), 256, 0, stream>>>(a3, msum);
  k_gram<<<dim3(2, 2, 32), 256, 0, stream>>>(a3, gram);
  k_trace<<<dim3(32), 256, 0, stream>>>(gram, msum, normA);
  k_initYZ<<<dim3(256, 32), 256, 0, stream>>>(gram, msum, normA, Ya, Za);
  float *Yc = Ya, *Zc = Za, *Yn = Yb, *Zn = Zb;
  for (int it = 0; it < 5; ++it) {
    k_ns_mm<<<dim3(16, 32), 256, 0, stream>>>(Zc, Yc, Tt, 0);          // T = 1.5I - 0.5 Z@Y
    k_ns_mm2<<<dim3(16, 32, 2), 256, 0, stream>>>(Yc, Tt, Zc, Yn, Zn); // Y'=Y@T, Z'=T@Z
    float* tmp;
    tmp = Yc; Yc = Yn; Yn = tmp;
    tmp = Zc; Zc = Zn; Zn = tmp;
  }
  k_v<<<dim3(32), 256, 0, stream>>>(Yc, normA, vbuf);
  k_attn<<<dim3(32), 256, 0, stream>>>(vbuf, caw1, cab1, caw2, cab2, attnb);
  k_final<<<dim3(36, 4, 32), 256, 0, stream>>>(a3, x, attnb, out);
  (void)in_sizes; (void)n_in; (void)out_size; (void)ws_size;
}

// Round 13
// 1362.906 us; speedup vs baseline: 1.0536x; 1.0536x over previous
//
#include <hip/hip_runtime.h>
#include <hip/hip_bf16.h>

#define Bn 32
#define Cn 256
#define Hn 48
#define Wn 48
#define HWn 2304
#define Pn 50
#define PPn 2500
#define K9 2304

typedef __attribute__((ext_vector_type(8))) short bf16x8;
typedef __attribute__((ext_vector_type(4))) float f32x4;

__device__ __forceinline__ void gload_lds16(const void* g, void* l) {
  __builtin_amdgcn_global_load_lds((const __attribute__((address_space(1))) void*)g,
                                   (__attribute__((address_space(3))) void*)l, 16, 0, 0);
}

// ---------------- zero halos of the two padded NHWC buffers ----------------
__global__ void k_zero_halo(__hip_bfloat16* p0, __hip_bfloat16* p1) {
  int hp = blockIdx.x, b = blockIdx.y, c = threadIdx.x;
  int h, w;
  if (hp < 50)       { h = 0;        w = hp; }
  else if (hp < 100) { h = 49;       w = hp - 50; }
  else if (hp < 148) { h = hp - 99;  w = 0; }
  else               { h = hp - 147; w = 49; }
  __hip_bfloat16* p = blockIdx.z == 0 ? p0 : p1;
  p[(((size_t)b * Pn + h) * Pn + w) * Cn + c] = __float2bfloat16(0.f);
}

// ---------------- weight repack: (O,C,3,3) f32 -> W2[o][t*256+ci] bf16 -----
__global__ void k_prep_w(const float* __restrict__ w, __hip_bfloat16* __restrict__ w2, int O) {
  int idx = blockIdx.x * 256 + threadIdx.x;
  if (idx >= O * K9) return;
  int o = idx / K9, k = idx - o * K9;
  int t = k >> 8, ci = k & 255;
  w2[idx] = __float2bfloat16(w[(size_t)(o * Cn + ci) * 9 + t]);
}

// ---------------- x NCHW f32 -> padded NHWC bf16 ---------------------------
__global__ void k_x_to_pad(const float* __restrict__ x, __hip_bfloat16* __restrict__ xp) {
  __shared__ float tile[64][65];
  int m0 = blockIdx.x * 64, c0 = blockIdx.y * 64, b = blockIdx.z;
  int tid = threadIdx.x;
#pragma unroll
  for (int p = 0; p < 16; ++p) {
    int cr = (tid >> 6) + p * 4;
    int mm = tid & 63;
    tile[cr][mm] = x[((size_t)(b * Cn + c0 + cr)) * HWn + m0 + mm];
  }
  __syncthreads();
#pragma unroll
  for (int p = 0; p < 16; ++p) {
    int c2 = tid & 63;
    int m2 = (tid >> 6) + p * 4;
    int mg = m0 + m2;
    int h = mg / 48, w = mg - h * 48;
    xp[(((size_t)b * Pn + h + 1) * Pn + (w + 1)) * Cn + c0 + c2] = __float2bfloat16(tile[c2][m2]);
  }
}

// ---------------- implicit conv GEMM (9-tap, NHWC padded in, bf16) ---------
// 1D grid, XCD-aware swizzle: each XCD gets a contiguous run of (mt,nt,b)
// blocks (= 4 whole batches) so the A-panel (1.28 MB/batch) + weights
// (<=2.36 MB) stay resident in that XCD's 4 MB L2.  nwg % 8 == 0 always.
// epi 0: NHWC out [b][m][O] (offsets).  epi 1: bias+relu -> padded NHWC interior.
// epi 2: bias -> NHWC [b][m][256] (a3).
__global__ __launch_bounds__(256, 2)
void k_conv_gemm(const __hip_bfloat16* __restrict__ inp, const __hip_bfloat16* __restrict__ w2,
                 const float* __restrict__ bias, __hip_bfloat16* __restrict__ out,
                 int O, int epi) {
  __shared__ __align__(16) __hip_bfloat16 As[128 * 64];
  __shared__ __align__(16) __hip_bfloat16 Bs[128 * 64];
  const int Nt = O >> 7;                 // N-tiles of 128
  const int nper = gridDim.x >> 3;       // nwg / 8
  const int wg = blockIdx.x;
  const int wgs = (wg & 7) * nper + (wg >> 3);   // bijective XCD swizzle (T1)
  const int mt = wgs % 18;
  const int rr = wgs / 18;
  const int nt = rr % Nt;
  const int b  = rr / Nt;
  const int tid = threadIdx.x;
  const int wv = tid >> 6, ln = tid & 63;
  const int wr = wv >> 1, wc = wv & 1;

  const int swz = ((ln & 7) ^ (ln >> 3)) * 8;  // element offset (8 elems = 16B chunks)
  int aSp[4];
  const __hip_bfloat16* w2b[4];
#pragma unroll
  for (int i = 0; i < 4; ++i) {
    int row = wv * 32 + i * 8 + (ln >> 3);
    int gm = mt * 128 + row;
    int hh = gm / 48, ww = gm - hh * 48;
    aSp[i] = hh * Pn + ww;
    w2b[i] = w2 + (size_t)(nt * 128 + row) * K9 + swz;
  }
  const __hip_bfloat16* inb = inp + (size_t)b * (PPn * Cn) + swz;

  f32x4 acc[4][4];
  f32x4 zero = {0.f, 0.f, 0.f, 0.f};
#pragma unroll
  for (int i = 0; i < 4; ++i)
#pragma unroll
    for (int j = 0; j < 4; ++j) acc[i][j] = zero;

  const int arow0 = wr * 64 + (ln & 15);
  const int brow0 = wc * 64 + (ln & 15);
  const int kb0 = (ln >> 4) * 16;
  const int sx = (ln & 7) << 4;

#pragma unroll 1
  for (int t = 0; t < 9; ++t) {
    const int dOff = (t / 3) * Pn + (t % 3);
#pragma unroll 1
    for (int ck = 0; ck < 4; ++ck) {
#pragma unroll
      for (int i = 0; i < 4; ++i) {
        gload_lds16(inb + (size_t)(aSp[i] + dOff) * Cn + ck * 64, (void*)(As + (wv * 4 + i) * 512));
        gload_lds16(w2b[i] + t * 256 + ck * 64, (void*)(Bs + (wv * 4 + i) * 512));
      }
      __syncthreads();
#pragma unroll
      for (int kk = 0; kk < 2; ++kk) {
        const int kb = kk * 64 + kb0;
        bf16x8 af[4], bfr[4];
#pragma unroll
        for (int mi = 0; mi < 4; ++mi) {
          int r = arow0 + mi * 16;
          af[mi] = *(const bf16x8*)((const char*)As + r * 128 + (kb ^ sx));
        }
#pragma unroll
        for (int ni = 0; ni < 4; ++ni) {
          int r = brow0 + ni * 16;
          bfr[ni] = *(const bf16x8*)((const char*)Bs + r * 128 + (kb ^ sx));
        }
#pragma unroll
        for (int mi = 0; mi < 4; ++mi)
#pragma unroll
          for (int ni = 0; ni < 4; ++ni)
            acc[mi][ni] = __builtin_amdgcn_mfma_f32_16x16x32_bf16(af[mi], bfr[ni], acc[mi][ni], 0, 0, 0);
      }
      __syncthreads();
    }
  }

#pragma unroll
  for (int mi = 0; mi < 4; ++mi)
#pragma unroll
    for (int ni = 0; ni < 4; ++ni)
#pragma unroll
      for (int j = 0; j < 4; ++j) {
        int ml = wr * 64 + mi * 16 + (ln >> 4) * 4 + j;
        int ol = wc * 64 + ni * 16 + (ln & 15);
        int gm = mt * 128 + ml;
        int go = nt * 128 + ol;
        float v = acc[mi][ni][j];
        if (epi == 0) {
          out[((size_t)b * HWn + gm) * (size_t)O + go] = __float2bfloat16(v);
        } else if (epi == 1) {
          v += bias[go];
          v = v > 0.f ? v : 0.f;
          int hh = gm / 48, ww = gm - hh * 48;
          out[(((size_t)b * Pn + hh + 1) * Pn + (ww + 1)) * Cn + go] = __float2bfloat16(v);
        } else {
          v += bias[go];
          out[((size_t)b * HWn + gm) * Cn + go] = __float2bfloat16(v);
        }
      }
}

// ---------------- ConvOffset2D bilinear resample ---------------------------
__global__ void k_resample(const __hip_bfloat16* __restrict__ img,  // padded NHWC
                           const __hip_bfloat16* __restrict__ off,  // [B][2304][512]
                           __hip_bfloat16* __restrict__ outp) {     // padded NHWC
  int q = blockIdx.x, b = blockIdx.y, c = threadIdx.x;
  int dlt = (q >= 1152) ? 1 : 0;
  int pos = 2 * q - dlt * HWn;
  size_t ob = ((size_t)b * HWn + pos) * 512 + 2 * c + dlt;
  float oy = __bfloat162float(off[ob]);
  float ox = __bfloat162float(off[ob + 512]);
  int gy = q / 48, gx = q - gy * 48;
  float y = fminf(fmaxf((float)gy + oy, 0.f), 47.f);
  float x = fminf(fmaxf((float)gx + ox, 0.f), 47.f);
  float fy = floorf(y), fx = floorf(x);
  int y0 = (int)fy, x0 = (int)fx;
  int y1 = min(y0 + 1, 47), x1 = min(x0 + 1, 47);
  float wy = y - fy, wx = x - fx;
  const __hip_bfloat16* ib = img + (size_t)b * (PPn * Cn) + c;
  float v00 = __bfloat162float(ib[(size_t)((y0 + 1) * Pn + x0 + 1) * Cn]);
  float v01 = __bfloat162float(ib[(size_t)((y0 + 1) * Pn + x1 + 1) * Cn]);
  float v10 = __bfloat162float(ib[(size_t)((y1 + 1) * Pn + x0 + 1) * Cn]);
  float v11 = __bfloat162float(ib[(size_t)((y1 + 1) * Pn + x1 + 1) * Cn]);
  float r = v00 * (1 - wy) * (1 - wx) + v01 * (1 - wy) * wx + v10 * wy * (1 - wx) + v11 * wy * wx;
  outp[(((size_t)b * Pn + gy + 1) * Pn + (gx + 1)) * Cn + c] = __float2bfloat16(r);
}

// ---------------- channel sums of a3 ---------------------------------------
__global__ void k_colmeans(const __hip_bfloat16* __restrict__ a3, float* __restrict__ msum) {
  int b = blockIdx.y, m0 = blockIdx.x * 128, c = threadIdx.x;
  const __hip_bfloat16* p = a3 + ((size_t)b * HWn + m0) * Cn + c;
  float s = 0.f;
  for (int r = 0; r < 128; ++r) s += __bfloat162float(p[(size_t)r * Cn]);
  atomicAdd(&msum[b * Cn + c], s);
}

// ---------------- Gram = a3^T a3 per batch (bf16 MFMA) ---------------------
__global__ __launch_bounds__(256, 2)
void k_gram(const __hip_bfloat16* __restrict__ a3, float* __restrict__ gram) {
  __shared__ __align__(16) __hip_bfloat16 Ti[64 * 128];
  __shared__ __align__(16) __hip_bfloat16 Tj[64 * 128];
  int it = blockIdx.x, jt = blockIdx.y, b = blockIdx.z;
  int tid = threadIdx.x, wv = tid >> 6, ln = tid & 63;
  int wr = wv >> 1, wc = wv & 1;
  f32x4 acc[4][4];
  f32x4 zero = {0.f, 0.f, 0.f, 0.f};
#pragma unroll
  for (int i = 0; i < 4; ++i)
#pragma unroll
    for (int j = 0; j < 4; ++j) acc[i][j] = zero;
  const __hip_bfloat16* base = a3 + (size_t)b * HWn * Cn;
#pragma unroll 1
  for (int m0 = 0; m0 < HWn; m0 += 64) {
#pragma unroll
    for (int i = 0; i < 4; ++i) {
      int row = (wv * 4 + i) * 4 + (ln >> 4);
      int ce = (ln & 15) * 8;
      gload_lds16(base + (size_t)(m0 + row) * Cn + it * 128 + ce, (void*)(Ti + (wv * 4 + i) * 512));
      gload_lds16(base + (size_t)(m0 + row) * Cn + jt * 128 + ce, (void*)(Tj + (wv * 4 + i) * 512));
    }
    __syncthreads();
#pragma unroll
    for (int kk = 0; kk < 2; ++kk) {
      bf16x8 af[4], bfr[4];
#pragma unroll
      for (int mi = 0; mi < 4; ++mi) {
        int il = wr * 64 + mi * 16 + (ln & 15);
        bf16x8 v;
#pragma unroll
        for (int j = 0; j < 8; ++j)
          v[j] = ((const short*)Ti)[(kk * 32 + (ln >> 4) * 8 + j) * 128 + il];
        af[mi] = v;
      }
#pragma unroll
      for (int ni = 0; ni < 4; ++ni) {
        int jl = wc * 64 + ni * 16 + (ln & 15);
        bf16x8 v;
#pragma unroll
        for (int j = 0; j < 8; ++j)
          v[j] = ((const short*)Tj)[(kk * 32 + (ln >> 4) * 8 + j) * 128 + jl];
        bfr[ni] = v;
      }
#pragma unroll
      for (int mi = 0; mi < 4; ++mi)
#pragma unroll
        for (int ni = 0; ni < 4; ++ni)
          acc[mi][ni] = __builtin_amdgcn_mfma_f32_16x16x32_bf16(af[mi], bfr[ni], acc[mi][ni], 0, 0, 0);
    }
    __syncthreads();
  }
#pragma unroll
  for (int mi = 0; mi < 4; ++mi)
#pragma unroll
    for (int ni = 0; ni < 4; ++ni)
#pragma unroll
      for (int j = 0; j < 4; ++j) {
        int gi = it * 128 + wr * 64 + mi * 16 + (ln >> 4) * 4 + j;
        int gj = jt * 128 + wc * 64 + ni * 16 + (ln & 15);
        gram[((size_t)b * Cn + gi) * Cn + gj] = acc[mi][ni][j];
      }
}

// ---------------- trace of cov ---------------------------------------------
__global__ void k_trace(const float* __restrict__ gram, const float* __restrict__ msum,
                        float* __restrict__ normA) {
  __shared__ float red[256];
  int b = blockIdx.x, i = threadIdx.x;
  float g = gram[((size_t)b * Cn + i) * Cn + i];
  float mu = msum[b * Cn + i] * (1.f / 2304.f);
  red[i] = g * (1.f / 2304.f) - mu * mu;
  __syncthreads();
  for (int s = 128; s > 0; s >>= 1) {
    if (i < s) red[i] += red[i + s];
    __syncthreads();
  }
  if (i == 0) normA[b] = red[0];
}

// ---------------- Y0 = cov/normA, Z0 = I -----------------------------------
__global__ void k_initYZ(const float* __restrict__ gram, const float* __restrict__ msum,
                         const float* __restrict__ normA, float* __restrict__ Y, float* __restrict__ Z) {
  int b = blockIdx.y;
  int idx = blockIdx.x * 256 + threadIdx.x;
  int i = idx >> 8, j = idx & 255;
  float mui = msum[b * Cn + i] * (1.f / 2304.f);
  float muj = msum[b * Cn + j] * (1.f / 2304.f);
  float cov = gram[((size_t)b << 16) + idx] * (1.f / 2304.f) - mui * muj;
  Y[((size_t)b << 16) + idx] = cov / normA[b];
  Z[((size_t)b << 16) + idx] = (i == j) ? 1.f : 0.f;
}

// ---------------- batched 256x256 fp32 matmul (NS) -------------------------
// mode 0: O = 1.5I - 0.5*(A@B);  mode 1: O = A@B
__global__ __launch_bounds__(256)
void k_ns_mm(const float* __restrict__ Ag, const float* __restrict__ Bg,
             float* __restrict__ Og, int mode) {
  __shared__ float As[16][65];
  __shared__ __align__(16) float Bs[16][64];
  int ti = blockIdx.x >> 2, tj = blockIdx.x & 3;
  int b = blockIdx.y;
  const float* A = Ag + ((size_t)b << 16);
  const float* B = Bg + ((size_t)b << 16);
  int tid = threadIdx.x, tx = tid & 15, ty = tid >> 4;
  float acc[4][4] = {};
#pragma unroll 1
  for (int k0 = 0; k0 < 256; k0 += 16) {
    {
      int k = tid & 15, r0 = tid >> 4;
#pragma unroll
      for (int p = 0; p < 4; ++p) {
        int r = r0 + p * 16;
        As[k][r] = A[(size_t)(ti * 64 + r) * 256 + k0 + k];
      }
      int cc = tid & 63, kb = tid >> 6;
#pragma unroll
      for (int p = 0; p < 4; ++p) {
        int k2 = kb + p * 4;
        Bs[k2][cc] = B[(size_t)(k0 + k2) * 256 + tj * 64 + cc];
      }
    }
    __syncthreads();
#pragma unroll
    for (int kk = 0; kk < 16; ++kk) {
      float4 bv = *(const float4*)&Bs[kk][tx * 4];
      float av[4];
#pragma unroll
      for (int i2 = 0; i2 < 4; ++i2) av[i2] = As[kk][ty * 4 + i2];
#pragma unroll
      for (int i2 = 0; i2 < 4; ++i2) {
        acc[i2][0] += av[i2] * bv.x;
        acc[i2][1] += av[i2] * bv.y;
        acc[i2][2] += av[i2] * bv.z;
        acc[i2][3] += av[i2] * bv.w;
      }
    }
    __syncthreads();
  }
#pragma unroll
  for (int i2 = 0; i2 < 4; ++i2) {
    int gi = ti * 64 + ty * 4 + i2;
#pragma unroll
    for (int j = 0; j < 4; ++j) {
      int gj = tj * 64 + tx * 4 + j;
      float v = acc[i2][j];
      if (mode == 0) v = ((gi == gj) ? 1.5f : 0.f) - 0.5f * v;
      Og[((size_t)b << 16) + (size_t)gi * 256 + gj] = v;
    }
  }
}

// ---- fused NS update: z=0 computes Yn=Yc@Tt, z=1 computes Zn=Tt@Zc --------
// Same body as k_ns_mm mode 1; operand triple selected by blockIdx.z.
__global__ __launch_bounds__(256)
void k_ns_mm2(const float* __restrict__ Ycg, const float* __restrict__ Ttg,
              const float* __restrict__ Zcg, float* __restrict__ Yng,
              float* __restrict__ Zng) {
  __shared__ float As[16][65];
  __shared__ __align__(16) float Bs[16][64];
  int ti = blockIdx.x >> 2, tj = blockIdx.x & 3;
  int b = blockIdx.y;
  const float* A;
  const float* B;
  float* O;
  if (blockIdx.z == 0) { A = Ycg; B = Ttg; O = Yng; }
  else                 { A = Ttg; B = Zcg; O = Zng; }
  A += ((size_t)b << 16);
  B += ((size_t)b << 16);
  int tid = threadIdx.x, tx = tid & 15, ty = tid >> 4;
  float acc[4][4] = {};
#pragma unroll 1
  for (int k0 = 0; k0 < 256; k0 += 16) {
    {
      int k = tid & 15, r0 = tid >> 4;
#pragma unroll
      for (int p = 0; p < 4; ++p) {
        int r = r0 + p * 16;
        As[k][r] = A[(size_t)(ti * 64 + r) * 256 + k0 + k];
      }
      int cc = tid & 63, kb = tid >> 6;
#pragma unroll
      for (int p = 0; p < 4; ++p) {
        int k2 = kb + p * 4;
        Bs[k2][cc] = B[(size_t)(k0 + k2) * 256 + tj * 64 + cc];
      }
    }
    __syncthreads();
#pragma unroll
    for (int kk = 0; kk < 16; ++kk) {
      float4 bv = *(const float4*)&Bs[kk][tx * 4];
      float av[4];
#pragma unroll
      for (int i2 = 0; i2 < 4; ++i2) av[i2] = As[kk][ty * 4 + i2];
#pragma unroll
      for (int i2 = 0; i2 < 4; ++i2) {
        acc[i2][0] += av[i2] * bv.x;
        acc[i2][1] += av[i2] * bv.y;
        acc[i2][2] += av[i2] * bv.z;
        acc[i2][3] += av[i2] * bv.w;
      }
    }
    __syncthreads();
  }
#pragma unroll
  for (int i2 = 0; i2 < 4; ++i2) {
    int gi = ti * 64 + ty * 4 + i2;
#pragma unroll
    for (int j = 0; j < 4; ++j) {
      int gj = tj * 64 + tx * 4 + j;
      O[((size_t)b << 16) + (size_t)gi * 256 + gj] = acc[i2][j];
    }
  }
}

// ---------------- v = sqrt(normA)/256 * colsum(Y) --------------------------
__global__ void k_v(const float* __restrict__ Y, const float* __restrict__ normA,
                    float* __restrict__ v) {
  int b = blockIdx.x, d = threadIdx.x;
  const float* p = Y + ((size_t)b << 16) + d;
  float s = 0.f;
  for (int c = 0; c < 256; ++c) s += p[(size_t)c * 256];
  v[b * Cn + d] = s * (1.f / 256.f) * sqrtf(normA[b]);
}

// ---------------- attention MLP --------------------------------------------
__global__ void k_attn(const float* __restrict__ v, const float* __restrict__ w1,
                       const float* __restrict__ b1, const float* __restrict__ w2,
                       const float* __restrict__ b2, float* __restrict__ attn) {
  __shared__ float sv[256], sh[32];
  int b = blockIdx.x, t = threadIdx.x;
  sv[t] = v[b * Cn + t];
  __syncthreads();
  if (t < 32) {
    float s = b1[t];
    for (int c = 0; c < 256; ++c) s += sv[c] * w1[t * 256 + c];
    sh[t] = fmaxf(s, 0.f);
  }
  __syncthreads();
  float s = b2[t];
  for (int j = 0; j < 32; ++j) s += sh[j] * w2[t * 32 + j];
  attn[b * Cn + t] = 1.f / (1.f + expf(-s));
}

// ---------------- out = attn*a3 + x (NHWC->NCHW) ---------------------------
__global__ void k_final(const __hip_bfloat16* __restrict__ a3, const float* __restrict__ x,
                        const float* __restrict__ attn, float* __restrict__ out) {
  __shared__ float tile[64][65];
  int m0 = blockIdx.x * 64, c0 = blockIdx.y * 64, b = blockIdx.z;
  int tid = threadIdx.x;
#pragma unroll
  for (int p = 0; p < 16; ++p) {
    int mr = (tid >> 6) + p * 4;
    int cl = tid & 63;
    tile[mr][cl] = __bfloat162float(a3[((size_t)b * HWn + m0 + mr) * Cn + c0 + cl]);
  }
  __syncthreads();
#pragma unroll
  for (int p = 0; p < 16; ++p) {
    int m2 = tid & 63;
    int c2 = (tid >> 6) + p * 4;
    size_t gidx = ((size_t)(b * Cn + c0 + c2)) * HWn + m0 + m2;
    out[gidx] = attn[b * Cn + c0 + c2] * tile[m2][c2] + x[gidx];
  }
}

// ===========================================================================
extern "C" void kernel_launch(void* const* d_in, const int* in_sizes, int n_in,
                              void* d_out, int out_size, void* d_ws, size_t ws_size,
                              hipStream_t stream) {
  const float* x      = (const float*)d_in[0];
  const float* off_w1 = (const float*)d_in[1];
  const float* off_w2 = (const float*)d_in[2];
  const float* c1w    = (const float*)d_in[3];
  const float* c1b    = (const float*)d_in[4];
  const float* c2w    = (const float*)d_in[5];
  const float* c2b    = (const float*)d_in[6];
  const float* caw1   = (const float*)d_in[7];
  const float* cab1   = (const float*)d_in[8];
  const float* caw2   = (const float*)d_in[9];
  const float* cab2   = (const float*)d_in[10];
  float* out = (float*)d_out;

  char* ws = (char*)d_ws;
  size_t o = 0;
  auto alloc = [&](size_t n) { char* p = ws + o; o = (o + n + 255) & ~(size_t)255; return p; };

  const size_t PADB = (size_t)Bn * PPn * Cn * 2;       // 40,960,000
  __hip_bfloat16* padA = (__hip_bfloat16*)alloc(PADB); // x_pad, later a1_pad
  __hip_bfloat16* padB = (__hip_bfloat16*)alloc(PADB); // a0_pad, later a2_pad
  char* offreg = alloc((size_t)Bn * HWn * 512 * 2);    // 75.5 MB, reused by NS bufs
  __hip_bfloat16* offb = (__hip_bfloat16*)offreg;
  __hip_bfloat16* a3   = (__hip_bfloat16*)alloc((size_t)Bn * HWn * Cn * 2);
  __hip_bfloat16* w2o1 = (__hip_bfloat16*)alloc((size_t)512 * K9 * 2);
  __hip_bfloat16* w2o2 = (__hip_bfloat16*)alloc((size_t)512 * K9 * 2);
  __hip_bfloat16* w2c1 = (__hip_bfloat16*)alloc((size_t)256 * K9 * 2);
  __hip_bfloat16* w2c2 = (__hip_bfloat16*)alloc((size_t)256 * K9 * 2);
  float* msum  = (float*)alloc(Bn * Cn * 4);
  float* normA = (float*)alloc(Bn * 4);
  float* vbuf  = (float*)alloc(Bn * Cn * 4);
  float* attnb = (float*)alloc(Bn * Cn * 4);
  // NS buffers overlay the (dead-by-then) offset region
  const size_t MB = (size_t)Bn * Cn * Cn * 4; // 8,388,608
  float* gram = (float*)(offreg + 0 * MB);
  float* Ya   = (float*)(offreg + 1 * MB);
  float* Za   = (float*)(offreg + 2 * MB);
  float* Yb   = (float*)(offreg + 3 * MB);
  float* Zb   = (float*)(offreg + 4 * MB);
  float* Tt   = (float*)(offreg + 5 * MB);

  k_zero_halo<<<dim3(196, 32, 2), 256, 0, stream>>>(padA, padB);
  k_prep_w<<<dim3(4608), 256, 0, stream>>>(off_w1, w2o1, 512);
  k_prep_w<<<dim3(4608), 256, 0, stream>>>(off_w2, w2o2, 512);
  k_prep_w<<<dim3(2304), 256, 0, stream>>>(c1w, w2c1, 256);
  k_prep_w<<<dim3(2304), 256, 0, stream>>>(c2w, w2c2, 256);
  k_x_to_pad<<<dim3(36, 4, 32), 256, 0, stream>>>(x, padA);

  // off1 = conv(x); a0 = resample(x, off1)   [1D grid, XCD-swizzled]
  k_conv_gemm<<<dim3(2304), 256, 0, stream>>>(padA, w2o1, nullptr, offb, 512, 0);
  k_resample<<<dim3(2304, 32), 256, 0, stream>>>(padA, offb, padB);
  // a1 = relu(conv1(a0))  (writes padA)
  k_conv_gemm<<<dim3(1152), 256, 0, stream>>>(padB, w2c1, c1b, padA, 256, 1);
  // off2 = conv(a1); a2 = resample(a1, off2) (writes padB)
  k_conv_gemm<<<dim3(2304), 256, 0, stream>>>(padA, w2o2, nullptr, offb, 512, 0);
  k_resample<<<dim3(2304, 32), 256, 0, stream>>>(padA, offb, padB);
  // a3 = conv2(a2)
  k_conv_gemm<<<dim3(1152), 256, 0, stream>>>(padB, w2c2, c2b, a3, 256, 2);

  // SOCA
  hipMemsetAsync(msum, 0, Bn * Cn * 4, stream);
  k_colmeans<<<dim3(18, 32), 256, 0, stream>>>(a3, msum);
  k_gram<<<dim3(2, 2, 32), 256, 0, stream>>>(a3, gram);
  k_trace<<<dim3(32), 256, 0, stream>>>(gram, msum, normA);
  k_initYZ<<<dim3(256, 32), 256, 0, stream>>>(gram, msum, normA, Ya, Za);
  float *Yc = Ya, *Zc = Za, *Yn = Yb, *Zn = Zb;
  for (int it = 0; it < 5; ++it) {
    k_ns_mm<<<dim3(16, 32), 256, 0, stream>>>(Zc, Yc, Tt, 0);          // T = 1.5I - 0.5 Z@Y
    k_ns_mm2<<<dim3(16, 32, 2), 256, 0, stream>>>(Yc, Tt, Zc, Yn, Zn); // Y'=Y@T, Z'=T@Z
    float* tmp;
    tmp = Yc; Yc = Yn; Yn = tmp;
    tmp = Zc; Zc = Zn; Zn = tmp;
  }
  k_v<<<dim3(32), 256, 0, stream>>>(Yc, normA, vbuf);
  k_attn<<<dim3(32), 256, 0, stream>>>(vbuf, caw1, cab1, caw2, cab2, attnb);
  k_final<<<dim3(36, 4, 32), 256, 0, stream>>>(a3, x, attnb, out);
  (void)in_sizes; (void)n_in; (void)out_size; (void)ws_size;
}